// Round 1
// baseline (246.985 us; speedup 1.0000x reference)
//
#include <hip/hip_runtime.h>
#include <hip/hip_bf16.h>

#define HH 8
#define DD 64
#define NN 256
#define Q1c 21
#define Q2c 21
#define MM 4096
#define KTOT 2048   // HH*NN
#define BN 64
#define BK 32

typedef __attribute__((ext_vector_type(8))) short short8;
typedef __attribute__((ext_vector_type(4))) float f32x4;
typedef __attribute__((ext_vector_type(4))) unsigned int u32x4;

__device__ inline unsigned short f2bf(float f) {
  __hip_bfloat16 h = __float2bfloat16(f);
  return *reinterpret_cast<unsigned short*>(&h);
}

// Kernel 1: e = Q^T K per head, softmax over j. Writes sf (f32 [h][i][j]) and
// sfT (bf16 bits, [i][h*256+j]) = A-operand of the big GEMM.
__global__ void k_softmax(const float* __restrict__ Q, const float* __restrict__ K,
                          float* __restrict__ sf, unsigned short* __restrict__ sfT) {
  int h = blockIdx.x >> 8;
  int i = blockIdx.x & 255;
  int j = threadIdx.x;
  __shared__ float qs[DD];
  __shared__ float red[4];
  if (j < DD) qs[j] = Q[(h*DD + j)*NN + i];
  __syncthreads();
  float e = 0.f;
#pragma unroll
  for (int d = 0; d < DD; ++d) e = fmaf(qs[d], K[(h*DD + d)*NN + j], e);
  float mx = e;
#pragma unroll
  for (int o = 32; o; o >>= 1) mx = fmaxf(mx, __shfl_xor(mx, o));
  if ((j & 63) == 0) red[j >> 6] = mx;
  __syncthreads();
  mx = fmaxf(fmaxf(red[0], red[1]), fmaxf(red[2], red[3]));
  float p = __expf(e - mx);
  float s = p;
#pragma unroll
  for (int o = 32; o; o >>= 1) s += __shfl_xor(s, o);
  __syncthreads();
  if ((j & 63) == 0) red[j >> 6] = s;
  __syncthreads();
  s = red[0] + red[1] + red[2] + red[3];
  p = p / s;
  sf[(h*NN + i)*NN + j] = p;
  sfT[i*KTOT + h*NN + j] = f2bf(p);
}

// Kernel 2: Mmat[h,k] = sum_{i,j} sf[h,i,j]*sf[k,i,j], upper-tri 36 entries via atomics.
__global__ void k_mmat(const float* __restrict__ sf, float* __restrict__ Mmat) {
  int i = blockIdx.x, j = threadIdx.x;
  float v[HH];
#pragma unroll
  for (int h = 0; h < HH; ++h) v[h] = sf[(h*NN + i)*NN + j];
  float pr[36];
  {
    int idx = 0;
#pragma unroll
    for (int h = 0; h < HH; ++h)
#pragma unroll
      for (int k = h; k < HH; ++k) pr[idx++] = v[h]*v[k];
  }
#pragma unroll
  for (int x = 0; x < 36; ++x) {
#pragma unroll
    for (int o = 32; o; o >>= 1) pr[x] += __shfl_xor(pr[x], o);
  }
  __shared__ float mm[4][36];
  int w = j >> 6;
  if ((j & 63) == 0) {
#pragma unroll
    for (int x = 0; x < 36; ++x) mm[w][x] = pr[x];
  }
  __syncthreads();
  if (j < 36) atomicAdd(&Mmat[j], mm[0][j] + mm[1][j] + mm[2][j] + mm[3][j]);
}

// Kernel 3: the big GEMM with on-the-fly gathered B and fused reduction epilogue.
// C[i, n=(a*4096+m)] = sum_{k=(h*256+j)} sfT[i,k] * V[h, a, Z2[j,m]]  (= G[i,m,a])
// Epilogue: Sexp[m] += sum_{i,a} exp(G);  Ene[m] += sum_i G * (Z1[i,m]==a)
__global__ __launch_bounds__(256) void k_gemm(
    const unsigned short* __restrict__ sfT, const float* __restrict__ Vf,
    const int* __restrict__ Z1, const int* __restrict__ Z2,
    float* __restrict__ Sexp, float* __restrict__ Ene) {
  __shared__ unsigned short Alds[NN * 40];      // 256 x 32, rows padded to 40 (80B)
  __shared__ unsigned short Blds[BN * 40];      // [col][k] transposed, padded
  __shared__ float Vrep[HH * 32 * Q2c];         // V[h, a_blk, :] replicated 32x per h

  const int t = threadIdx.x;
  const int n0 = blockIdx.x * BN;
  const int a_blk = n0 / MM;       // 0..20, constant per block (4096 % 64 == 0)
  const int m0 = n0 % MM;

  for (int x = t; x < HH*32*Q2c; x += 256) {
    int h = x / (32*Q2c);
    int rem = x - h*(32*Q2c);
    int c = rem % Q2c;
    Vrep[x] = Vf[h*(Q1c*Q2c) + a_blk*Q2c + c];
  }

  f32x4 acc[4][4];
#pragma unroll
  for (int p = 0; p < 4; ++p)
#pragma unroll
    for (int q = 0; q < 4; ++q) acc[p][q] = (f32x4){0.f, 0.f, 0.f, 0.f};

  const int w  = t >> 6;
  const int l  = t & 63;
  const int lr = l & 15;          // fragment row/col lane index
  const int lk = l >> 4;          // k-group / C-row-group
  const int nnB = t & 63;         // B staging: column within tile
  const int kk8 = (t >> 6) * 8;   // B staging: 8 k's per thread
  const float* vrep_lane_base_unused = nullptr; (void)vrep_lane_base_unused;
  const int rep = (l & 31) * Q2c; // per-lane replica (gcd(21,32)=1 -> bank spread)

  __syncthreads();

  for (int k0 = 0; k0 < KTOT; k0 += BK) {
    const int h  = k0 >> 8;       // constant within K-step (32 | 256)
    const int j0 = k0 & 255;
    // ---- stage A: 256x32 bf16 from sfT (L2-resident) ----
#pragma unroll
    for (int p = 0; p < 4; ++p) {
      int i  = p*64 + (t >> 2);
      int kk = (t & 3) * 8;
      u32x4 v = *reinterpret_cast<const u32x4*>(sfT + i*KTOT + k0 + kk);
      *reinterpret_cast<u32x4*>(&Alds[i*40 + kk]) = v;
    }
    // ---- stage B: gather V[h, a_blk, Z2[j, m]] -> bf16, write [col][k] ----
    {
      const int m = m0 + nnB;
      const float* vh = &Vrep[h*(32*Q2c) + rep];
      unsigned int pw[4];
#pragma unroll
      for (int rp = 0; rp < 4; ++rp) {
        int c0 = Z2[(j0 + kk8 + 2*rp    )*MM + m];
        int c1 = Z2[(j0 + kk8 + 2*rp + 1)*MM + m];
        unsigned short b0 = f2bf(vh[c0]);
        unsigned short b1 = f2bf(vh[c1]);
        pw[rp] = (unsigned int)b0 | ((unsigned int)b1 << 16);
      }
      u32x4 pk = {pw[0], pw[1], pw[2], pw[3]};
      *reinterpret_cast<u32x4*>(&Blds[nnB*40 + kk8]) = pk;
    }
    __syncthreads();
    // ---- fragments + MFMA ----
    short8 af[4], bfv[4];
#pragma unroll
    for (int mr = 0; mr < 4; ++mr) {
      int row = w*64 + mr*16 + lr;
      af[mr] = *reinterpret_cast<const short8*>(&Alds[row*40 + lk*8]);
    }
#pragma unroll
    for (int nc = 0; nc < 4; ++nc) {
      int col = nc*16 + lr;
      bfv[nc] = *reinterpret_cast<const short8*>(&Blds[col*40 + lk*8]);
    }
#pragma unroll
    for (int mr = 0; mr < 4; ++mr)
#pragma unroll
      for (int nc = 0; nc < 4; ++nc)
        acc[mr][nc] = __builtin_amdgcn_mfma_f32_16x16x32_bf16(af[mr], bfv[nc], acc[mr][nc], 0, 0, 0);
    __syncthreads();
  }

  // ---- fused epilogue: exp-sum and Z1-selected sum per column m ----
#pragma unroll
  for (int nc = 0; nc < 4; ++nc) {
    const int m = m0 + nc*16 + lr;      // C/D: col = lane&15
    float se = 0.f, en = 0.f;
#pragma unroll
    for (int mr = 0; mr < 4; ++mr) {
#pragma unroll
      for (int r = 0; r < 4; ++r) {
        int irow = w*64 + mr*16 + lk*4 + r;   // C/D: row = (lane>>4)*4 + reg
        float g = acc[mr][nc][r];
        se += __expf(g);
        int z = Z1[irow*MM + m];
        en += (z == a_blk) ? g : 0.f;
      }
    }
    se += __shfl_xor(se, 16); se += __shfl_xor(se, 32);
    en += __shfl_xor(en, 16); en += __shfl_xor(en, 32);
    if (lk == 0) {
      atomicAdd(&Sexp[m], se);
      atomicAdd(&Ene[m], en);
    }
  }
}

// Kernel 4: pl = -sum_m w[m]*(Ene[m] - log(Sexp[m] + 235)); block 16 adds reg term.
__global__ void k_final(const float* __restrict__ Sexp, const float* __restrict__ Ene,
                        const float* __restrict__ wts, const float* __restrict__ Mmat,
                        const float* __restrict__ Vf, float* __restrict__ out) {
  __shared__ float r4[4];
  float val = 0.f;
  if (blockIdx.x < 16) {
    int m = blockIdx.x * 256 + threadIdx.x;
    val = -wts[m] * (Ene[m] - logf(Sexp[m] + 235.0f));
  } else {
    int t = threadIdx.x;
    if (t < 64) {
      int h = t >> 3, k = t & 7;
      float dot = 0.f;
      for (int x = 0; x < Q1c*Q2c; ++x) dot += Vf[h*(Q1c*Q2c)+x] * Vf[k*(Q1c*Q2c)+x];
      int hh = (h < k) ? h : k;
      int kk = (h < k) ? k : h;
      int idx = hh*8 - (hh*(hh-1))/2 + (kk - hh);   // upper-tri index
      val = 0.001f * Mmat[idx] * dot;               // LAMBD = 0.001
    }
  }
#pragma unroll
  for (int o = 32; o; o >>= 1) val += __shfl_xor(val, o);
  int w = threadIdx.x >> 6;
  if ((threadIdx.x & 63) == 0) r4[w] = val;
  __syncthreads();
  if (threadIdx.x == 0) atomicAdd(out, r4[0] + r4[1] + r4[2] + r4[3]);
}

extern "C" void kernel_launch(void* const* d_in, const int* in_sizes, int n_in,
                              void* d_out, int out_size, void* d_ws, size_t ws_size,
                              hipStream_t stream) {
  const float* Q   = (const float*)d_in[0];
  const float* K   = (const float*)d_in[1];
  const float* V   = (const float*)d_in[2];
  const int*   Z1  = (const int*)d_in[3];
  const int*   Z2  = (const int*)d_in[4];
  const float* wts = (const float*)d_in[5];
  float* out = (float*)d_out;

  char* ws = (char*)d_ws;
  float*          sf   = (float*)ws;                               // 2 MB
  unsigned short* sfT  = (unsigned short*)(ws + (2u << 20));       // 1 MB
  float*          Sexp = (float*)(ws + 3u*(1u << 20));             // 16 KB
  float*          Ene  = (float*)(ws + 3u*(1u << 20) + (16u<<10)); // 16 KB
  float*          Mmat = (float*)(ws + 3u*(1u << 20) + (32u<<10)); // 36 floats

  hipMemsetAsync(out, 0, sizeof(float), stream);
  hipMemsetAsync(ws + 3u*(1u << 20), 0, (32u << 10) + 256, stream);

  k_softmax<<<dim3(2048), dim3(256), 0, stream>>>(Q, K, sf, sfT);
  k_mmat   <<<dim3(256),  dim3(256), 0, stream>>>(sf, Mmat);
  k_gemm   <<<dim3(1344), dim3(256), 0, stream>>>(sfT, V, Z1, Z2, Sexp, Ene);
  k_final  <<<dim3(17),   dim3(256), 0, stream>>>(Sexp, Ene, wts, Mmat, V, out);
}

// Round 2
// 190.281 us; speedup vs baseline: 1.2980x; 1.2980x over previous
//
#include <hip/hip_runtime.h>
#include <hip/hip_bf16.h>

#define HH 8
#define DD 64
#define NN 256
#define Q1c 21
#define Q2c 21
#define MM 4096
#define KTOT 2048   // HH*NN
#define BN 64
#define BK 32

typedef __attribute__((ext_vector_type(8))) short short8;
typedef __attribute__((ext_vector_type(4))) float f32x4;
typedef __attribute__((ext_vector_type(4))) unsigned int u32x4;

__device__ inline unsigned short f2bf(float f) {
  __hip_bfloat16 h = __float2bfloat16(f);
  return *reinterpret_cast<unsigned short*>(&h);
}

// Kernel 1: e = Q^T K per head, softmax over j. Writes sf (f32 [h][i][j]) and
// sfF: bf16 A-operand pre-fragmented as [ks=k/32][i][k%32] so k_gemm's A-frag
// loads are fully-coalesced 1KB global reads (A never touches LDS there).
__global__ void k_softmax(const float* __restrict__ Q, const float* __restrict__ K,
                          float* __restrict__ sf, unsigned short* __restrict__ sfF) {
  int h = blockIdx.x >> 8;
  int i = blockIdx.x & 255;
  int j = threadIdx.x;
  __shared__ float qs[DD];
  __shared__ float red[4];
  if (j < DD) qs[j] = Q[(h*DD + j)*NN + i];
  __syncthreads();
  float e = 0.f;
#pragma unroll
  for (int d = 0; d < DD; ++d) e = fmaf(qs[d], K[(h*DD + d)*NN + j], e);
  float mx = e;
#pragma unroll
  for (int o = 32; o; o >>= 1) mx = fmaxf(mx, __shfl_xor(mx, o));
  if ((j & 63) == 0) red[j >> 6] = mx;
  __syncthreads();
  mx = fmaxf(fmaxf(red[0], red[1]), fmaxf(red[2], red[3]));
  float p = __expf(e - mx);
  float s = p;
#pragma unroll
  for (int o = 32; o; o >>= 1) s += __shfl_xor(s, o);
  __syncthreads();
  if ((j & 63) == 0) red[j >> 6] = s;
  __syncthreads();
  s = red[0] + red[1] + red[2] + red[3];
  p = p / s;
  sf[(h*NN + i)*NN + j] = p;
  int ks = h*8 + (j >> 5);
  sfF[((ks*NN + i) << 5) + (j & 31)] = f2bf(p);
}

// Kernel 2: Mmat[h,k] upper-tri 36 entries via atomics.
__global__ void k_mmat(const float* __restrict__ sf, float* __restrict__ Mmat) {
  int i = blockIdx.x, j = threadIdx.x;
  float v[HH];
#pragma unroll
  for (int h = 0; h < HH; ++h) v[h] = sf[(h*NN + i)*NN + j];
  float pr[36];
  {
    int idx = 0;
#pragma unroll
    for (int h = 0; h < HH; ++h)
#pragma unroll
      for (int k = h; k < HH; ++k) pr[idx++] = v[h]*v[k];
  }
#pragma unroll
  for (int x = 0; x < 36; ++x) {
#pragma unroll
    for (int o = 32; o; o >>= 1) pr[x] += __shfl_xor(pr[x], o);
  }
  __shared__ float mm[4][36];
  int w = j >> 6;
  if ((j & 63) == 0) {
#pragma unroll
    for (int x = 0; x < 36; ++x) mm[w][x] = pr[x];
  }
  __syncthreads();
  if (j < 36) atomicAdd(&Mmat[j], mm[0][j] + mm[1][j] + mm[2][j] + mm[3][j]);
}

// Kernel 3: big GEMM. A from global (pre-fragmented sfF, L2-hot). B gathered
// per K-step via ds_bpermute from a single VGPR holding V[h][a_blk][0..20]
// (bf16, lane c holds value c). Double-buffered B in LDS, one raw barrier per
// step; next-step A/Z2 prefetches issued before the barrier stay in flight.
__global__ __launch_bounds__(256) void k_gemm(
    const unsigned short* __restrict__ sfF, const float* __restrict__ Vf,
    const int* __restrict__ Z1, const int* __restrict__ Z2,
    float* __restrict__ Sexp, float* __restrict__ Ene) {
  __shared__ unsigned short Blds[2][BN * 40];   // [col][k] rows padded to 40 shorts

  const int t  = threadIdx.x;
  const int w  = t >> 6;
  const int l  = t & 63;
  const int lr = l & 15;
  const int lk = l >> 4;
  const int colB = t & 63;        // B staging: column within tile
  const int kk8  = w * 8;         // B staging: 8 k's per wave

  const int n0 = blockIdx.x * BN;
  const int a_blk = n0 / MM;      // 0..20 (4096 % 64 == 0)
  const int m0 = n0 - a_blk * MM;
  const int mB = m0 + colB;

  f32x4 acc[4][4];
#pragma unroll
  for (int p = 0; p < 4; ++p)
#pragma unroll
    for (int q = 0; q < 4; ++q) acc[p][q] = (f32x4){0.f, 0.f, 0.f, 0.f};

  // ---- prologue: V row (h=0), Z2 indices (ks=0), A frags (ks=0) ----
  float vv = (l < Q1c) ? Vf[a_blk*Q2c + l] : 0.f;
  int ccur[8];
#pragma unroll
  for (int r = 0; r < 8; ++r) ccur[r] = Z2[(kk8 + r)*MM + mB];
  short8 acur[4];
#pragma unroll
  for (int mr = 0; mr < 4; ++mr)
    acur[mr] = *reinterpret_cast<const short8*>(sfF + (w*64 + mr*16 + lr)*32 + lk*8);
  int vcur = (int)f2bf(vv);
  float vvn = 0.f;
  int buf = 0;

  for (int h = 0; h < HH; ++h) {
#pragma unroll
    for (int s = 0; s < 8; ++s) {
      const int ks = h*8 + s;
      // ---- gather + pack: B[k][col] = bf16(V[h][a_blk][Z2[j,m]]) ----
      unsigned int pw[4];
#pragma unroll
      for (int p = 0; p < 4; ++p) {
        int b0 = __builtin_amdgcn_ds_bpermute(ccur[2*p]     << 2, vcur);
        int b1 = __builtin_amdgcn_ds_bpermute(ccur[2*p + 1] << 2, vcur);
        pw[p] = __builtin_amdgcn_perm((unsigned)b1, (unsigned)b0, 0x05040100u);
      }
      u32x4 pk = {pw[0], pw[1], pw[2], pw[3]};
      *reinterpret_cast<u32x4*>(&Blds[buf][colB*40 + kk8]) = pk;
      // ---- prefetch next step (global; stays in flight across raw barrier) ----
      if (s == 0)
        vvn = ((h+1) < HH && l < Q1c) ? Vf[(h+1)*(Q1c*Q2c) + a_blk*Q2c + l] : 0.f;
      int cn[8];
      {
        const int j0n = ((s+1) & 7) * 32;   // Z2 rows are h-independent
#pragma unroll
        for (int r = 0; r < 8; ++r) cn[r] = Z2[(j0n + kk8 + r)*MM + mB];
      }
      short8 an[4];
      {
        const int ksn = (ks < 63) ? ks + 1 : 63;
        const unsigned short* ab = sfF + (size_t)ksn * (NN*32);
#pragma unroll
        for (int mr = 0; mr < 4; ++mr)
          an[mr] = *reinterpret_cast<const short8*>(ab + (w*64 + mr*16 + lr)*32 + lk*8);
      }
      // ---- LDS-drain barrier (vmcnt stays in flight) ----
      asm volatile("s_waitcnt lgkmcnt(0)" ::: "memory");
      __builtin_amdgcn_s_barrier();
      __builtin_amdgcn_sched_barrier(0);
      // ---- B frags + MFMA ----
      short8 bfv[4];
#pragma unroll
      for (int nc = 0; nc < 4; ++nc)
        bfv[nc] = *reinterpret_cast<const short8*>(&Blds[buf][(nc*16 + lr)*40 + lk*8]);
#pragma unroll
      for (int mr = 0; mr < 4; ++mr)
#pragma unroll
        for (int nc = 0; nc < 4; ++nc)
          acc[mr][nc] = __builtin_amdgcn_mfma_f32_16x16x32_bf16(acur[mr], bfv[nc], acc[mr][nc], 0, 0, 0);
      // ---- rotate prefetched regs (SSA, no real moves) ----
#pragma unroll
      for (int r = 0; r < 8; ++r) ccur[r] = cn[r];
#pragma unroll
      for (int mr = 0; mr < 4; ++mr) acur[mr] = an[mr];
      buf ^= 1;
    }
    vcur = (int)f2bf(vvn);
  }

  // ---- fused epilogue: exp-sum and Z1-selected sum per column m ----
#pragma unroll
  for (int nc = 0; nc < 4; ++nc) {
    const int m = m0 + nc*16 + lr;          // C/D: col = lane&15
    float se = 0.f, en = 0.f;
#pragma unroll
    for (int mr = 0; mr < 4; ++mr) {
#pragma unroll
      for (int r = 0; r < 4; ++r) {
        int irow = w*64 + mr*16 + lk*4 + r; // C/D: row = (lane>>4)*4 + reg
        float g = acc[mr][nc][r];
        se += __expf(g);
        int z = Z1[irow*MM + m];
        en += (z == a_blk) ? g : 0.f;
      }
    }
    se += __shfl_xor(se, 16); se += __shfl_xor(se, 32);
    en += __shfl_xor(en, 16); en += __shfl_xor(en, 32);
    if (lk == 0) {
      atomicAdd(&Sexp[m], se);
      atomicAdd(&Ene[m], en);
    }
  }
}

// Kernel 4: pl = -sum_m w[m]*(Ene[m] - log(Sexp[m] + 235)); block 16 adds reg term.
__global__ void k_final(const float* __restrict__ Sexp, const float* __restrict__ Ene,
                        const float* __restrict__ wts, const float* __restrict__ Mmat,
                        const float* __restrict__ Vf, float* __restrict__ out) {
  __shared__ float r4[4];
  float val = 0.f;
  if (blockIdx.x < 16) {
    int m = blockIdx.x * 256 + threadIdx.x;
    val = -wts[m] * (Ene[m] - logf(Sexp[m] + 235.0f));
  } else {
    int t = threadIdx.x;
    if (t < 64) {
      int h = t >> 3, k = t & 7;
      float dot = 0.f;
      for (int x = 0; x < Q1c*Q2c; ++x) dot += Vf[h*(Q1c*Q2c)+x] * Vf[k*(Q1c*Q2c)+x];
      int hh = (h < k) ? h : k;
      int kk = (h < k) ? k : h;
      int idx = hh*8 - (hh*(hh-1))/2 + (kk - hh);   // upper-tri index
      val = 0.001f * Mmat[idx] * dot;               // LAMBD = 0.001
    }
  }
#pragma unroll
  for (int o = 32; o; o >>= 1) val += __shfl_xor(val, o);
  int w = threadIdx.x >> 6;
  if ((threadIdx.x & 63) == 0) r4[w] = val;
  __syncthreads();
  if (threadIdx.x == 0) atomicAdd(out, r4[0] + r4[1] + r4[2] + r4[3]);
}

extern "C" void kernel_launch(void* const* d_in, const int* in_sizes, int n_in,
                              void* d_out, int out_size, void* d_ws, size_t ws_size,
                              hipStream_t stream) {
  const float* Q   = (const float*)d_in[0];
  const float* K   = (const float*)d_in[1];
  const float* V   = (const float*)d_in[2];
  const int*   Z1  = (const int*)d_in[3];
  const int*   Z2  = (const int*)d_in[4];
  const float* wts = (const float*)d_in[5];
  float* out = (float*)d_out;

  char* ws = (char*)d_ws;
  float*          sf   = (float*)ws;                               // 2 MB
  unsigned short* sfF  = (unsigned short*)(ws + (2u << 20));       // 1 MB
  float*          Sexp = (float*)(ws + 3u*(1u << 20));             // 16 KB
  float*          Ene  = (float*)(ws + 3u*(1u << 20) + (16u<<10)); // 16 KB
  float*          Mmat = (float*)(ws + 3u*(1u << 20) + (32u<<10)); // 36 floats

  hipMemsetAsync(out, 0, sizeof(float), stream);
  hipMemsetAsync(ws + 3u*(1u << 20), 0, (32u << 10) + 256, stream);

  k_softmax<<<dim3(2048), dim3(256), 0, stream>>>(Q, K, sf, sfF);
  k_mmat   <<<dim3(256),  dim3(256), 0, stream>>>(sf, Mmat);
  k_gemm   <<<dim3(1344), dim3(256), 0, stream>>>(sfF, V, Z1, Z2, Sexp, Ene);
  k_final  <<<dim3(17),   dim3(256), 0, stream>>>(Sexp, Ene, wts, Mmat, V, out);
}

// Round 3
// 150.304 us; speedup vs baseline: 1.6432x; 1.2660x over previous
//
#include <hip/hip_runtime.h>
#include <hip/hip_bf16.h>

#define HH 8
#define DD 64
#define NN 256
#define Q1c 21
#define Q2c 21
#define MM 4096
#define KTOT 2048   // HH*NN
#define BN 64

typedef __attribute__((ext_vector_type(8))) short short8;
typedef __attribute__((ext_vector_type(4))) float f32x4;
typedef __attribute__((ext_vector_type(4))) unsigned int u32x4;

__device__ inline unsigned short f2bf(float f) {
  __hip_bfloat16 h = __float2bfloat16(f);
  return *reinterpret_cast<unsigned short*>(&h);
}

// Kernel 0: pack Z2 (int32 [j][m]) -> Z2t bytes [j/8][m][8] so k_gemm loads
// 8 indices with one dwordx2.
__global__ void k_pack(const int* __restrict__ Z2, unsigned char* __restrict__ Z2t) {
  int jb = blockIdx.x >> 4;                       // 0..31
  int m  = ((blockIdx.x & 15) << 8) + threadIdx.x;
  unsigned lo = 0, hi = 0;
#pragma unroll
  for (int r = 0; r < 4; ++r) lo |= ((unsigned)Z2[(jb*8 + r)*MM + m] & 255u) << (8*r);
#pragma unroll
  for (int r = 0; r < 4; ++r) hi |= ((unsigned)Z2[(jb*8 + 4 + r)*MM + m] & 255u) << (8*r);
  uint2 v; v.x = lo; v.y = hi;
  *reinterpret_cast<uint2*>(Z2t + ((size_t)jb*MM + m)*8) = v;
}

// Kernel 1: e = Q^T K per head, softmax over j. Writes sf (f32 [h][i][j]) and
// sfF: bf16 A-operand pre-fragmented as [ks=k/32][i][k%32].
__global__ void k_softmax(const float* __restrict__ Q, const float* __restrict__ K,
                          float* __restrict__ sf, unsigned short* __restrict__ sfF) {
  int h = blockIdx.x >> 8;
  int i = blockIdx.x & 255;
  int j = threadIdx.x;
  __shared__ float qs[DD];
  __shared__ float red[4];
  if (j < DD) qs[j] = Q[(h*DD + j)*NN + i];
  __syncthreads();
  float e = 0.f;
#pragma unroll
  for (int d = 0; d < DD; ++d) e = fmaf(qs[d], K[(h*DD + d)*NN + j], e);
  float mx = e;
#pragma unroll
  for (int o = 32; o; o >>= 1) mx = fmaxf(mx, __shfl_xor(mx, o));
  if ((j & 63) == 0) red[j >> 6] = mx;
  __syncthreads();
  mx = fmaxf(fmaxf(red[0], red[1]), fmaxf(red[2], red[3]));
  float p = __expf(e - mx);
  float s = p;
#pragma unroll
  for (int o = 32; o; o >>= 1) s += __shfl_xor(s, o);
  __syncthreads();
  if ((j & 63) == 0) red[j >> 6] = s;
  __syncthreads();
  s = red[0] + red[1] + red[2] + red[3];
  p = p / s;
  sf[(h*NN + i)*NN + j] = p;
  int ks = h*8 + (j >> 5);
  sfF[((ks*NN + i) << 5) + (j & 31)] = f2bf(p);
}

// Kernel 2: Mmat[h,k] upper-tri 36 entries via atomics.
__global__ void k_mmat(const float* __restrict__ sf, float* __restrict__ Mmat) {
  int i = blockIdx.x, j = threadIdx.x;
  float v[HH];
#pragma unroll
  for (int h = 0; h < HH; ++h) v[h] = sf[(h*NN + i)*NN + j];
  float pr[36];
  {
    int idx = 0;
#pragma unroll
    for (int h = 0; h < HH; ++h)
#pragma unroll
      for (int k = h; k < HH; ++k) pr[idx++] = v[h]*v[k];
  }
#pragma unroll
  for (int x = 0; x < 36; ++x) {
#pragma unroll
    for (int o = 32; o; o >>= 1) pr[x] += __shfl_xor(pr[x], o);
  }
  __shared__ float mm[4][36];
  int w = j >> 6;
  if ((j & 63) == 0) {
#pragma unroll
    for (int x = 0; x < 36; ++x) mm[w][x] = pr[x];
  }
  __syncthreads();
  if (j < 36) atomicAdd(&Mmat[j], mm[0][j] + mm[1][j] + mm[2][j] + mm[3][j]);
}

// Kernel 3: big GEMM, 2-h packed gather. Superstep = 64 k (heads 2hp,2hp+1
// share Z2 indices: one bpermute yields both bf16 values packed in a dword).
// Per superstep: barrier -> ds_read B frags -> bpermute(next) -> 32 MFMA ->
// ds_write(next buf). A-frags prefetched from global (sfF, L2-hot).
__global__ __launch_bounds__(256) void k_gemm(
    const unsigned short* __restrict__ sfF, const float* __restrict__ Vf,
    const int* __restrict__ Z1, const unsigned char* __restrict__ Z2t,
    float* __restrict__ Sexp, float* __restrict__ Ene) {
  __shared__ unsigned short Blds[2][2][BN * 40];  // [buf][tile][col*40 + k]

  const int t  = threadIdx.x;
  const int w  = t >> 6;
  const int l  = t & 63;
  const int lr = l & 15;
  const int lk = l >> 4;
  const int colB = l;

  const int n0 = blockIdx.x * BN;
  const int a_blk = n0 / MM;       // 0..20 (4096 % 64 == 0)
  const int m0 = n0 - a_blk * MM;
  const int mB = m0 + colB;

  f32x4 acc[4][4];
#pragma unroll
  for (int p = 0; p < 4; ++p)
#pragma unroll
    for (int q = 0; q < 4; ++q) acc[p][q] = (f32x4){0.f, 0.f, 0.f, 0.f};

  // V pair for hp=0 (h=0 lo16, h=1 hi16), per lane c<21
  unsigned vcur, vnxt;
  {
    float a0 = (l < Q1c) ? Vf[0*(Q1c*Q2c) + a_blk*Q2c + l] : 0.f;
    float a1 = (l < Q1c) ? Vf[1*(Q1c*Q2c) + a_blk*Q2c + l] : 0.f;
    vcur = ((unsigned)f2bf(a1) << 16) | (unsigned)f2bf(a0);
    vnxt = vcur;
  }

  const unsigned char* zbase = Z2t + (size_t)mB * 8;
  // z: 8 indices (bytes) for superstep-to-gather; jblk = js*4 + w
  uint2 z = *reinterpret_cast<const uint2*>(zbase + (size_t)w * (MM*8));

  // A frags for s=0: ks0 = 0, ks1 = 8
  short8 af[8];
#pragma unroll
  for (int tile = 0; tile < 2; ++tile)
#pragma unroll
    for (int mr = 0; mr < 4; ++mr)
      af[tile*4+mr] = *reinterpret_cast<const short8*>(
          sfF + (((tile*8)*NN + (w*64 + mr*16 + lr)) << 5) + lk*8);

  // ---- prologue: gather + write superstep 0 into buf 0 ----
  {
    unsigned zlo = z.x, zhi = z.y;
    unsigned g[8];
#pragma unroll
    for (int r = 0; r < 8; ++r) {
      int c = (int)((r < 4 ? (zlo >> (8*r)) : (zhi >> (8*(r-4)))) & 255u);
      g[r] = (unsigned)__builtin_amdgcn_ds_bpermute(c << 2, (int)vcur);
    }
    unsigned pw0[4], pw1[4];
#pragma unroll
    for (int p = 0; p < 4; ++p) {
      pw0[p] = __builtin_amdgcn_perm(g[2*p+1], g[2*p], 0x05040100u);
      pw1[p] = __builtin_amdgcn_perm(g[2*p+1], g[2*p], 0x07060302u);
    }
    u32x4 q0 = {pw0[0], pw0[1], pw0[2], pw0[3]};
    u32x4 q1 = {pw1[0], pw1[1], pw1[2], pw1[3]};
    *reinterpret_cast<u32x4*>(&Blds[0][0][colB*40 + w*8]) = q0;
    *reinterpret_cast<u32x4*>(&Blds[0][1][colB*40 + w*8]) = q1;
  }
  // z for s=1 (jblk = 1*4 + w)
  z = *reinterpret_cast<const uint2*>(zbase + (size_t)(4 + w) * (MM*8));

  for (int hp = 0; hp < 4; ++hp) {
#pragma unroll
    for (int js = 0; js < 8; ++js) {
      const int s = hp*8 + js;
      const int buf = s & 1;
      asm volatile("s_waitcnt lgkmcnt(0)" ::: "memory");
      __builtin_amdgcn_s_barrier();
      __builtin_amdgcn_sched_barrier(0);
      // ---- B fragments (current superstep) ----
      short8 bf0[4], bf1[4];
#pragma unroll
      for (int nc = 0; nc < 4; ++nc)
        bf0[nc] = *reinterpret_cast<const short8*>(&Blds[buf][0][(nc*16 + lr)*40 + lk*8]);
#pragma unroll
      for (int nc = 0; nc < 4; ++nc)
        bf1[nc] = *reinterpret_cast<const short8*>(&Blds[buf][1][(nc*16 + lr)*40 + lk*8]);
      // ---- gather NEXT superstep (hides under MFMA) ----
      unsigned vuse = (js == 7) ? vnxt : vcur;
      unsigned pw0[4], pw1[4];
      {
        unsigned zlo = z.x, zhi = z.y;
        unsigned g[8];
#pragma unroll
        for (int r = 0; r < 8; ++r) {
          int c = (int)((r < 4 ? (zlo >> (8*r)) : (zhi >> (8*(r-4)))) & 255u);
          g[r] = (unsigned)__builtin_amdgcn_ds_bpermute(c << 2, (int)vuse);
        }
#pragma unroll
        for (int p = 0; p < 4; ++p) {
          pw0[p] = __builtin_amdgcn_perm(g[2*p+1], g[2*p], 0x05040100u);
          pw1[p] = __builtin_amdgcn_perm(g[2*p+1], g[2*p], 0x07060302u);
        }
      }
      // ---- MFMA (32) ----
#pragma unroll
      for (int mr = 0; mr < 4; ++mr)
#pragma unroll
        for (int nc = 0; nc < 4; ++nc)
          acc[mr][nc] = __builtin_amdgcn_mfma_f32_16x16x32_bf16(af[mr], bf0[nc], acc[mr][nc], 0, 0, 0);
#pragma unroll
      for (int mr = 0; mr < 4; ++mr)
#pragma unroll
        for (int nc = 0; nc < 4; ++nc)
          acc[mr][nc] = __builtin_amdgcn_mfma_f32_16x16x32_bf16(af[4+mr], bf1[nc], acc[mr][nc], 0, 0, 0);
      // ---- write next superstep's tiles ----
      {
        u32x4 q0 = {pw0[0], pw0[1], pw0[2], pw0[3]};
        u32x4 q1 = {pw1[0], pw1[1], pw1[2], pw1[3]};
        *reinterpret_cast<u32x4*>(&Blds[buf^1][0][colB*40 + w*8]) = q0;
        *reinterpret_cast<u32x4*>(&Blds[buf^1][1][colB*40 + w*8]) = q1;
      }
      // ---- prefetches (global; in flight across next barrier) ----
      if (js == 0) {
        int hpn = (hp < 3) ? hp + 1 : 3;
        float b0 = (l < Q1c) ? Vf[(2*hpn)*(Q1c*Q2c) + a_blk*Q2c + l] : 0.f;
        float b1 = (l < Q1c) ? Vf[(2*hpn+1)*(Q1c*Q2c) + a_blk*Q2c + l] : 0.f;
        vnxt = ((unsigned)f2bf(b1) << 16) | (unsigned)f2bf(b0);
      }
      {
        int s2 = s + 2; if (s2 > 31) s2 = 31;
        int jb2 = (s2 & 7)*4 + w;
        z = *reinterpret_cast<const uint2*>(zbase + (size_t)jb2 * (MM*8));
        int s1 = s + 1; if (s1 > 31) s1 = 31;
        int hp1 = s1 >> 3, js1 = s1 & 7;
        const unsigned short* a0 = sfF + (((hp1*16 + js1)*NN) << 5);
        const unsigned short* a1 = sfF + (((hp1*16 + 8 + js1)*NN) << 5);
        short8 an[8];
#pragma unroll
        for (int mr = 0; mr < 4; ++mr)
          an[mr] = *reinterpret_cast<const short8*>(a0 + ((w*64 + mr*16 + lr) << 5) + lk*8);
#pragma unroll
        for (int mr = 0; mr < 4; ++mr)
          an[4+mr] = *reinterpret_cast<const short8*>(a1 + ((w*64 + mr*16 + lr) << 5) + lk*8);
#pragma unroll
        for (int f = 0; f < 8; ++f) af[f] = an[f];
      }
      if (js == 7) vcur = vnxt;
    }
  }

  // ---- fused epilogue: exp-sum and Z1-selected sum per column m ----
#pragma unroll
  for (int nc = 0; nc < 4; ++nc) {
    const int m = m0 + nc*16 + lr;          // C/D: col = lane&15
    float se = 0.f, en = 0.f;
#pragma unroll
    for (int mr = 0; mr < 4; ++mr) {
#pragma unroll
      for (int r = 0; r < 4; ++r) {
        int irow = w*64 + mr*16 + lk*4 + r; // C/D: row = (lane>>4)*4 + reg
        float g = acc[mr][nc][r];
        se += __expf(g);
        int zz = Z1[irow*MM + m];
        en += (zz == a_blk) ? g : 0.f;
      }
    }
    se += __shfl_xor(se, 16); se += __shfl_xor(se, 32);
    en += __shfl_xor(en, 16); en += __shfl_xor(en, 32);
    if (lk == 0) {
      atomicAdd(&Sexp[m], se);
      atomicAdd(&Ene[m], en);
    }
  }
}

// Kernel 4: pl = -sum_m w[m]*(Ene[m] - log(Sexp[m] + 235)); block 16 adds reg term.
__global__ void k_final(const float* __restrict__ Sexp, const float* __restrict__ Ene,
                        const float* __restrict__ wts, const float* __restrict__ Mmat,
                        const float* __restrict__ Vf, float* __restrict__ out) {
  __shared__ float r4[4];
  float val = 0.f;
  if (blockIdx.x < 16) {
    int m = blockIdx.x * 256 + threadIdx.x;
    val = -wts[m] * (Ene[m] - logf(Sexp[m] + 235.0f));
  } else {
    int t = threadIdx.x;
    if (t < 64) {
      int h = t >> 3, k = t & 7;
      float dot = 0.f;
      for (int x = 0; x < Q1c*Q2c; ++x) dot += Vf[h*(Q1c*Q2c)+x] * Vf[k*(Q1c*Q2c)+x];
      int hh = (h < k) ? h : k;
      int kk = (h < k) ? k : h;
      int idx = hh*8 - (hh*(hh-1))/2 + (kk - hh);   // upper-tri index
      val = 0.001f * Mmat[idx] * dot;               // LAMBD = 0.001
    }
  }
#pragma unroll
  for (int o = 32; o; o >>= 1) val += __shfl_xor(val, o);
  int w = threadIdx.x >> 6;
  if ((threadIdx.x & 63) == 0) r4[w] = val;
  __syncthreads();
  if (threadIdx.x == 0) atomicAdd(out, r4[0] + r4[1] + r4[2] + r4[3]);
}

extern "C" void kernel_launch(void* const* d_in, const int* in_sizes, int n_in,
                              void* d_out, int out_size, void* d_ws, size_t ws_size,
                              hipStream_t stream) {
  const float* Q   = (const float*)d_in[0];
  const float* K   = (const float*)d_in[1];
  const float* V   = (const float*)d_in[2];
  const int*   Z1  = (const int*)d_in[3];
  const int*   Z2  = (const int*)d_in[4];
  const float* wts = (const float*)d_in[5];
  float* out = (float*)d_out;

  char* ws = (char*)d_ws;
  float*          sf   = (float*)ws;                               // 2 MB
  unsigned short* sfF  = (unsigned short*)(ws + (2u << 20));       // 1 MB
  unsigned char*  Z2t  = (unsigned char*)(ws + (3u << 20));        // 1 MB
  float*          Sexp = (float*)(ws + (4u << 20));                // 16 KB
  float*          Ene  = (float*)(ws + (4u << 20) + (16u << 10));  // 16 KB
  float*          Mmat = (float*)(ws + (4u << 20) + (32u << 10));  // 36 floats

  hipMemsetAsync(out, 0, sizeof(float), stream);
  hipMemsetAsync(ws + (4u << 20), 0, (32u << 10) + 256, stream);

  k_pack   <<<dim3(512),  dim3(256), 0, stream>>>(Z2, Z2t);
  k_softmax<<<dim3(2048), dim3(256), 0, stream>>>(Q, K, sf, sfF);
  k_mmat   <<<dim3(256),  dim3(256), 0, stream>>>(sf, Mmat);
  k_gemm   <<<dim3(1344), dim3(256), 0, stream>>>(sfF, V, Z1, Z2t, Sexp, Ene);
  k_final  <<<dim3(17),   dim3(256), 0, stream>>>(Sexp, Ene, wts, Mmat, V, out);
}